// Round 1
// baseline (471.654 us; speedup 1.0000x reference)
//
#include <hip/hip_runtime.h>
#include <stdint.h>

#define AS1 __attribute__((address_space(1)))
#define AS3 __attribute__((address_space(3)))

typedef __bf16 bf16x8 __attribute__((ext_vector_type(8)));
typedef float f32x4 __attribute__((ext_vector_type(4)));
typedef unsigned short u16x8 __attribute__((ext_vector_type(8)));

__device__ __forceinline__ unsigned short f2bf(float f) {
  unsigned int u = __builtin_bit_cast(unsigned int, f);
  u += 0x7fff + ((u >> 16) & 1);   // RNE
  return (unsigned short)(u >> 16);
}
__device__ __forceinline__ float bf2f(unsigned short h) {
  return __builtin_bit_cast(float, (unsigned int)h << 16);
}

// ---------------- kernel 1: x fp32 -> bf16 ----------------
__global__ __launch_bounds__(256) void cvt_x_kernel(const float* __restrict__ in,
                                                    unsigned short* __restrict__ out) {
  long i = ((long)blockIdx.x * 256 + threadIdx.x) * 8;
  float4 a = *(const float4*)(in + i);
  float4 b = *(const float4*)(in + i + 4);
  u16x8 v;
  v[0] = f2bf(a.x); v[1] = f2bf(a.y); v[2] = f2bf(a.z); v[3] = f2bf(a.w);
  v[4] = f2bf(b.x); v[5] = f2bf(b.y); v[6] = f2bf(b.z); v[7] = f2bf(b.w);
  *(u16x8*)(out + i) = v;
}

// ---------------- kernel 2: Wkv_t[n][k] = [Wk|Wv][k][n], bf16 ----------------
__global__ __launch_bounds__(256) void prep_wkvt_kernel(const float* __restrict__ Wk,
                                                        const float* __restrict__ Wv,
                                                        unsigned short* __restrict__ Wkvt) {
  int idx = blockIdx.x * 256 + threadIdx.x;   // 1024*512 total
  int nn = idx >> 9;
  int kk = idx & 511;
  float v = (nn < 512) ? Wk[kk * 512 + nn] : Wv[kk * 512 + (nn - 512)];
  Wkvt[idx] = f2bf(v);
}

// ---------------- kernel 3: KV = x @ [Wk|Wv] + bias, bf16 out ----------------
// A: 65536 x 512 bf16 (row-major). Bt: 1024 x 512 bf16 (N-major, i.e. W^T).
// C: 65536 x 1024 bf16. 128x128 tile per block, 4 waves of 64x64, BK=32.
__global__ __launch_bounds__(256) void kv_gemm_kernel(const unsigned short* __restrict__ A,
                                                      const unsigned short* __restrict__ Bt,
                                                      const float* __restrict__ bk,
                                                      const float* __restrict__ bv,
                                                      unsigned short* __restrict__ KV) {
  __shared__ unsigned short As[128 * 32];
  __shared__ unsigned short Bs[128 * 32];

  const int tid = threadIdx.x;
  const int wave = tid >> 6;
  const int lane = tid & 63;
  const int bm = blockIdx.x;   // 0..511
  const int bn = blockIdx.y;   // 0..7
  const int wm = wave >> 1;    // 0..1
  const int wn = wave & 1;     // 0..1

  f32x4 acc[4][4] = {};

  const long a_base = (long)bm * 128 * 512;
  const long b_base = (long)bn * 128 * 512;
  const int ldrow = lane >> 2;        // 0..15
  const int ldkq = (lane & 3) * 8;    // bf16 offset within 32-wide k-slice

  for (int k0 = 0; k0 < 512; k0 += 32) {
#pragma unroll
    for (int r = 0; r < 2; ++r) {
      const int row0 = r * 64 + wave * 16;            // wave-uniform
      const int row = row0 + ldrow;
      const unsigned short* ga = A + a_base + (long)row * 512 + k0 + ldkq;
      const unsigned short* gb = Bt + b_base + (long)row * 512 + k0 + ldkq;
      __builtin_amdgcn_global_load_lds(
          (const AS1 unsigned int*)(uintptr_t)ga,
          (AS3 unsigned int*)(uintptr_t)(As + row0 * 32), 16, 0, 0);
      __builtin_amdgcn_global_load_lds(
          (const AS1 unsigned int*)(uintptr_t)gb,
          (AS3 unsigned int*)(uintptr_t)(Bs + row0 * 32), 16, 0, 0);
    }
    __syncthreads();

    const int mrow = lane & 15;
    const int kq8 = (lane >> 4) * 8;
    bf16x8 af[4], bfr[4];
#pragma unroll
    for (int mi = 0; mi < 4; ++mi)
      af[mi] = *(const bf16x8*)&As[(wm * 64 + mi * 16 + mrow) * 32 + kq8];
#pragma unroll
    for (int ni = 0; ni < 4; ++ni)
      bfr[ni] = *(const bf16x8*)&Bs[(wn * 64 + ni * 16 + mrow) * 32 + kq8];
#pragma unroll
    for (int mi = 0; mi < 4; ++mi)
#pragma unroll
      for (int ni = 0; ni < 4; ++ni)
        acc[mi][ni] = __builtin_amdgcn_mfma_f32_16x16x32_bf16(af[mi], bfr[ni], acc[mi][ni], 0, 0, 0);
    __syncthreads();
  }

  // epilogue: C/D layout col=lane&15, row=(lane>>4)*4+reg
  const int col_l = lane & 15;
  const int rgrp = (lane >> 4) * 4;
#pragma unroll
  for (int ni = 0; ni < 4; ++ni) {
    const int col = bn * 128 + wn * 64 + ni * 16 + col_l;
    const float bias = (col < 512) ? bk[col] : bv[col - 512];
#pragma unroll
    for (int mi = 0; mi < 4; ++mi) {
      const long row = (long)bm * 128 + wm * 64 + mi * 16 + rgrp;
      unsigned short* outp = KV + row * 1024 + col;
#pragma unroll
      for (int r2 = 0; r2 < 4; ++r2)
        outp[(long)r2 * 1024] = f2bf(acc[mi][ni][r2] + bias);
    }
  }
}

// ---------------- kernel 4: fused Q-proj + attention + O-proj (fp32) ----------------
// one workgroup (256 threads) per (b,s); KV rows: (bs*256+n)*1024, [0,512)=K, [512,1024)=V
__global__ __launch_bounds__(256) void attn_kernel(const float* __restrict__ x,
                                                   const float* __restrict__ Wq,
                                                   const float* __restrict__ bq,
                                                   const unsigned short* __restrict__ KV,
                                                   const float* __restrict__ Wo,
                                                   const float* __restrict__ bo,
                                                   float* __restrict__ out) {
  const int bs = blockIdx.x;   // 0..255
  const int t = threadIdx.x;   // 0..255

  __shared__ float x0_s[512];
  __shared__ float q_s[512];
  __shared__ float p_s[8][256];
  __shared__ float ctx_s[512];

  const float* xrow = x + (long)bs * 256 * 512;   // token 0 of (b,s)
  if (t < 128) *(float4*)&x0_s[t * 4] = *(const float4*)&xrow[t * 4];
  __syncthreads();

  // Q projection (fp32): thread t owns cols t and t+256 (coalesced Wq rows)
  {
    float q0 = bq[t], q1 = bq[t + 256];
#pragma unroll 4
    for (int k = 0; k < 512; ++k) {
      const float xv = x0_s[k];
      q0 += xv * Wq[k * 512 + t];
      q1 += xv * Wq[k * 512 + t + 256];
    }
    q_s[t] = q0;
    q_s[t + 256] = q1;
  }
  __syncthreads();

  // logits: thread t handles token n=t, all 8 heads, K in bf16
  {
    const unsigned short* krow = KV + ((long)bs * 256 + t) * 1024;
#pragma unroll
    for (int h = 0; h < 8; ++h) {
      float dot = 0.f;
#pragma unroll
      for (int d = 0; d < 64; d += 8) {
        u16x8 kv8 = *(const u16x8*)&krow[h * 64 + d];
#pragma unroll
        for (int j = 0; j < 8; ++j) dot += q_s[h * 64 + d + j] * bf2f(kv8[j]);
      }
      p_s[h][t] = dot * 0.125f;
    }
  }
  __syncthreads();

  // softmax: wave w owns heads 2w, 2w+1
  {
    const int wave = t >> 6, lane = t & 63;
#pragma unroll
    for (int hh = 0; hh < 2; ++hh) {
      const int h = wave * 2 + hh;
      float l0 = p_s[h][lane], l1 = p_s[h][lane + 64];
      float l2 = p_s[h][lane + 128], l3 = p_s[h][lane + 192];
      float m = fmaxf(fmaxf(l0, l1), fmaxf(l2, l3));
      for (int o = 32; o; o >>= 1) m = fmaxf(m, __shfl_xor(m, o));
      float e0 = __expf(l0 - m), e1 = __expf(l1 - m);
      float e2 = __expf(l2 - m), e3 = __expf(l3 - m);
      float s = e0 + e1 + e2 + e3;
      for (int o = 32; o; o >>= 1) s += __shfl_xor(s, o);
      const float inv = 1.f / s;
      p_s[h][lane] = e0 * inv;
      p_s[h][lane + 64] = e1 * inv;
      p_s[h][lane + 128] = e2 * inv;
      p_s[h][lane + 192] = e3 * inv;
    }
  }
  __syncthreads();

  // ctx: thread t owns dims 2t,2t+1 (head t>>5); coalesced V row reads
  {
    const int h = t >> 5;
    const int d0 = t * 2;
    float c0 = 0.f, c1 = 0.f;
    const unsigned short* vbase = KV + (long)bs * 256 * 1024 + 512 + d0;
#pragma unroll 4
    for (int n = 0; n < 256; ++n) {
      const float a = p_s[h][n];
      const unsigned int vv = *(const unsigned int*)(vbase + (long)n * 1024);
      c0 += a * bf2f((unsigned short)(vv & 0xffffu));
      c1 += a * bf2f((unsigned short)(vv >> 16));
    }
    ctx_s[d0] = c0;
    ctx_s[d0 + 1] = c1;
  }
  __syncthreads();

  // O projection (fp32)
  {
    float o0 = bo[t], o1 = bo[t + 256];
#pragma unroll 4
    for (int k = 0; k < 512; ++k) {
      const float cv = ctx_s[k];
      o0 += cv * Wo[k * 512 + t];
      o1 += cv * Wo[k * 512 + t + 256];
    }
    out[(long)bs * 512 + t] = o0;
    out[(long)bs * 512 + t + 256] = o1;
  }
}

extern "C" void kernel_launch(void* const* d_in, const int* in_sizes, int n_in,
                              void* d_out, int out_size, void* d_ws, size_t ws_size,
                              hipStream_t stream) {
  (void)in_sizes; (void)n_in; (void)out_size; (void)ws_size;
  const float* x  = (const float*)d_in[0];
  const float* Wq = (const float*)d_in[1];
  const float* bq = (const float*)d_in[2];
  const float* Wk = (const float*)d_in[3];
  const float* bk = (const float*)d_in[4];
  const float* Wv = (const float*)d_in[5];
  const float* bv = (const float*)d_in[6];
  const float* Wo = (const float*)d_in[7];
  const float* bo = (const float*)d_in[8];
  float* out = (float*)d_out;

  unsigned short* xb   = (unsigned short*)d_ws;          // 65536*512  bf16 = 64 MiB
  unsigned short* wkvt = xb + (size_t)33554432;          // 1024*512   bf16 =  1 MiB
  unsigned short* kv   = wkvt + (size_t)524288;          // 65536*1024 bf16 = 128 MiB

  cvt_x_kernel<<<16384, 256, 0, stream>>>(x, xb);
  prep_wkvt_kernel<<<2048, 256, 0, stream>>>(Wk, Wv, wkvt);
  kv_gemm_kernel<<<dim3(512, 8), 256, 0, stream>>>(xb, wkvt, bk, bv, kv);
  attn_kernel<<<256, 256, 0, stream>>>(x, Wq, bq, kv, Wo, bo, out);
}

// Round 2
// 388.506 us; speedup vs baseline: 1.2140x; 1.2140x over previous
//
#include <hip/hip_runtime.h>
#include <stdint.h>

#define AS1 __attribute__((address_space(1)))
#define AS3 __attribute__((address_space(3)))

typedef __bf16 bf16x8 __attribute__((ext_vector_type(8)));
typedef float f32x4 __attribute__((ext_vector_type(4)));
typedef unsigned short u16x8 __attribute__((ext_vector_type(8)));

__device__ __forceinline__ unsigned short f2bf(float f) {
  unsigned int u = __builtin_bit_cast(unsigned int, f);
  u += 0x7fff + ((u >> 16) & 1);   // RNE
  return (unsigned short)(u >> 16);
}
__device__ __forceinline__ float bf2f(unsigned short h) {
  return __builtin_bit_cast(float, (unsigned int)h << 16);
}

// ---------------- kernel 1: x fp32 -> bf16 ----------------
__global__ __launch_bounds__(256) void cvt_x_kernel(const float* __restrict__ in,
                                                    unsigned short* __restrict__ out) {
  long i = ((long)blockIdx.x * 256 + threadIdx.x) * 8;
  float4 a = *(const float4*)(in + i);
  float4 b = *(const float4*)(in + i + 4);
  u16x8 v;
  v[0] = f2bf(a.x); v[1] = f2bf(a.y); v[2] = f2bf(a.z); v[3] = f2bf(a.w);
  v[4] = f2bf(b.x); v[5] = f2bf(b.y); v[6] = f2bf(b.z); v[7] = f2bf(b.w);
  *(u16x8*)(out + i) = v;
}

// ---------------- kernel 2: Wt[n][k] = [Wk|Wv|Wo][k][n], bf16 ----------------
__global__ __launch_bounds__(256) void prep_w_kernel(const float* __restrict__ Wk,
                                                     const float* __restrict__ Wv,
                                                     const float* __restrict__ Wo,
                                                     unsigned short* __restrict__ Wt) {
  int idx = blockIdx.x * 256 + threadIdx.x;   // 1536*512 total
  int nn = idx >> 9;
  int kk = idx & 511;
  float v;
  if (nn < 512)       v = Wk[kk * 512 + nn];
  else if (nn < 1024) v = Wv[kk * 512 + (nn - 512)];
  else                v = Wo[kk * 512 + (nn - 1024)];
  Wt[idx] = f2bf(v);
}

// ---------------- kernel 3: KV = x @ [Wk|Wv] + bias, bf16 out ----------------
// A: 65536 x 512 bf16. Bt: 1024 x 512 bf16 (N-major). C: 65536 x 1024 bf16.
// 128x128 tile, 4 waves of 64x64, BK=32. grid.x = bn (fast) for B-tile L2 reuse.
__global__ __launch_bounds__(256) void kv_gemm_kernel(const unsigned short* __restrict__ A,
                                                      const unsigned short* __restrict__ Bt,
                                                      const float* __restrict__ bk,
                                                      const float* __restrict__ bv,
                                                      unsigned short* __restrict__ KV) {
  __shared__ unsigned short As[128 * 32];
  __shared__ unsigned short Bs[128 * 32];

  const int tid = threadIdx.x;
  const int wave = tid >> 6;
  const int lane = tid & 63;
  const int bn = blockIdx.x;   // 0..7
  const int bm = blockIdx.y;   // 0..511
  const int wm = wave >> 1;
  const int wn = wave & 1;

  f32x4 acc[4][4] = {};

  const long a_base = (long)bm * 128 * 512;
  const long b_base = (long)bn * 128 * 512;
  const int ldrow = lane >> 2;
  const int ldkq = (lane & 3) * 8;

  for (int k0 = 0; k0 < 512; k0 += 32) {
#pragma unroll
    for (int r = 0; r < 2; ++r) {
      const int row0 = r * 64 + wave * 16;
      const int row = row0 + ldrow;
      const unsigned short* ga = A + a_base + (long)row * 512 + k0 + ldkq;
      const unsigned short* gb = Bt + b_base + (long)row * 512 + k0 + ldkq;
      __builtin_amdgcn_global_load_lds(
          (const AS1 unsigned int*)(uintptr_t)ga,
          (AS3 unsigned int*)(uintptr_t)(As + row0 * 32), 16, 0, 0);
      __builtin_amdgcn_global_load_lds(
          (const AS1 unsigned int*)(uintptr_t)gb,
          (AS3 unsigned int*)(uintptr_t)(Bs + row0 * 32), 16, 0, 0);
    }
    __syncthreads();

    const int mrow = lane & 15;
    const int kq8 = (lane >> 4) * 8;
    bf16x8 af[4], bfr[4];
#pragma unroll
    for (int mi = 0; mi < 4; ++mi)
      af[mi] = *(const bf16x8*)&As[(wm * 64 + mi * 16 + mrow) * 32 + kq8];
#pragma unroll
    for (int ni = 0; ni < 4; ++ni)
      bfr[ni] = *(const bf16x8*)&Bs[(wn * 64 + ni * 16 + mrow) * 32 + kq8];
#pragma unroll
    for (int mi = 0; mi < 4; ++mi)
#pragma unroll
      for (int ni = 0; ni < 4; ++ni)
        acc[mi][ni] = __builtin_amdgcn_mfma_f32_16x16x32_bf16(af[mi], bfr[ni], acc[mi][ni], 0, 0, 0);
    __syncthreads();
  }

  const int col_l = lane & 15;
  const int rgrp = (lane >> 4) * 4;
#pragma unroll
  for (int ni = 0; ni < 4; ++ni) {
    const int col = bn * 128 + wn * 64 + ni * 16 + col_l;
    const float bias = (col < 512) ? bk[col] : bv[col - 512];
#pragma unroll
    for (int mi = 0; mi < 4; ++mi) {
      const long row = (long)bm * 128 + wm * 64 + mi * 16 + rgrp;
      unsigned short* outp = KV + row * 1024 + col;
#pragma unroll
      for (int r2 = 0; r2 < 4; ++r2)
        outp[(long)r2 * 1024] = f2bf(acc[mi][ni][r2] + bias);
    }
  }
}

// ---------------- kernel 4: per-(bs,head) fused Q-proj + attention ----------------
// grid (256, 8): one WG per (bs, head). Writes ctx as bf16 (256 x 512 row-major).
__global__ __launch_bounds__(256) void attn_core_kernel(const float* __restrict__ x,
                                                        const float* __restrict__ Wq,
                                                        const float* __restrict__ bq,
                                                        const unsigned short* __restrict__ KV,
                                                        unsigned short* __restrict__ ctxb) {
  const int bs = blockIdx.x;   // 0..255
  const int h  = blockIdx.y;   // 0..7
  const int t  = threadIdx.x;  // 0..255
  const int c  = t & 63;       // dim within head / col
  const int g  = t >> 6;       // wave / k-group

  __shared__ float x0_s[512];
  __shared__ float part_s[4][64];
  __shared__ float q_s[64];
  __shared__ float p_s[256];
  __shared__ float red_s[4];

  const float* xrow = x + (long)bs * 256 * 512;   // token 0 of (b,s)
  if (t < 128) *(float4*)&x0_s[t * 4] = *(const float4*)&xrow[t * 4];
  __syncthreads();

  // Q-proj slice for this head: q[c] = sum_k x0[k] * Wq[k][h*64+c]
  {
    float p = 0.f;
    const float* wq = Wq + (long)(g * 128) * 512 + h * 64 + c;
#pragma unroll 4
    for (int k = 0; k < 128; ++k)
      p += x0_s[g * 128 + k] * wq[(long)k * 512];
    part_s[g][c] = p;
  }
  __syncthreads();
  if (t < 64) q_s[t] = part_s[0][t] + part_s[1][t] + part_s[2][t] + part_s[3][t] + bq[h * 64 + t];
  __syncthreads();

  // logits: thread t = token t, K row is one 128B cache line
  float l;
  {
    const unsigned short* krow = KV + ((long)bs * 256 + t) * 1024 + h * 64;
    float dot = 0.f;
#pragma unroll
    for (int d = 0; d < 64; d += 8) {
      u16x8 k8 = *(const u16x8*)(krow + d);
#pragma unroll
      for (int j = 0; j < 8; ++j) dot += q_s[d + j] * bf2f(k8[j]);
    }
    l = dot * 0.125f;
  }

  // block softmax over 256 logits
  {
    float m = l;
    for (int o = 32; o; o >>= 1) m = fmaxf(m, __shfl_xor(m, o));
    if ((t & 63) == 0) red_s[g] = m;
    __syncthreads();
    m = fmaxf(fmaxf(red_s[0], red_s[1]), fmaxf(red_s[2], red_s[3]));
    const float e = __expf(l - m);
    float s = e;
    for (int o = 32; o; o >>= 1) s += __shfl_xor(s, o);
    __syncthreads();
    if ((t & 63) == 0) red_s[g] = s;
    __syncthreads();
    s = red_s[0] + red_s[1] + red_s[2] + red_s[3];
    p_s[t] = e / s;
  }
  __syncthreads();

  // ctx: thread (g,c) sums 64 tokens for dim c; V row slice is one 128B line
  {
    float acc = 0.f;
    const unsigned short* vbase = KV + ((long)bs * 256 + g * 64) * 1024 + 512 + h * 64 + c;
#pragma unroll 4
    for (int n = 0; n < 64; ++n)
      acc += p_s[g * 64 + n] * bf2f(vbase[(long)n * 1024]);
    part_s[g][c] = acc;
  }
  __syncthreads();
  if (t < 64) {
    const float v = part_s[0][t] + part_s[1][t] + part_s[2][t] + part_s[3][t];
    ctxb[(long)bs * 512 + h * 64 + t] = f2bf(v);
  }
}

// ---------------- kernel 5: out = ctx(bf16) @ Wo + bo, fp32 out ----------------
// A: 256 x 512 bf16. Bt: 512 x 512 bf16 (N-major). grid (4 bn, 2 bm).
__global__ __launch_bounds__(256) void oproj_gemm_kernel(const unsigned short* __restrict__ A,
                                                         const unsigned short* __restrict__ Bt,
                                                         const float* __restrict__ bo,
                                                         float* __restrict__ out) {
  __shared__ unsigned short As[128 * 32];
  __shared__ unsigned short Bs[128 * 32];

  const int tid = threadIdx.x;
  const int wave = tid >> 6;
  const int lane = tid & 63;
  const int bn = blockIdx.x;   // 0..3
  const int bm = blockIdx.y;   // 0..1
  const int wm = wave >> 1;
  const int wn = wave & 1;

  f32x4 acc[4][4] = {};

  const long a_base = (long)bm * 128 * 512;
  const long b_base = (long)bn * 128 * 512;
  const int ldrow = lane >> 2;
  const int ldkq = (lane & 3) * 8;

  for (int k0 = 0; k0 < 512; k0 += 32) {
#pragma unroll
    for (int r = 0; r < 2; ++r) {
      const int row0 = r * 64 + wave * 16;
      const int row = row0 + ldrow;
      const unsigned short* ga = A + a_base + (long)row * 512 + k0 + ldkq;
      const unsigned short* gb = Bt + b_base + (long)row * 512 + k0 + ldkq;
      __builtin_amdgcn_global_load_lds(
          (const AS1 unsigned int*)(uintptr_t)ga,
          (AS3 unsigned int*)(uintptr_t)(As + row0 * 32), 16, 0, 0);
      __builtin_amdgcn_global_load_lds(
          (const AS1 unsigned int*)(uintptr_t)gb,
          (AS3 unsigned int*)(uintptr_t)(Bs + row0 * 32), 16, 0, 0);
    }
    __syncthreads();

    const int mrow = lane & 15;
    const int kq8 = (lane >> 4) * 8;
    bf16x8 af[4], bfr[4];
#pragma unroll
    for (int mi = 0; mi < 4; ++mi)
      af[mi] = *(const bf16x8*)&As[(wm * 64 + mi * 16 + mrow) * 32 + kq8];
#pragma unroll
    for (int ni = 0; ni < 4; ++ni)
      bfr[ni] = *(const bf16x8*)&Bs[(wn * 64 + ni * 16 + mrow) * 32 + kq8];
#pragma unroll
    for (int mi = 0; mi < 4; ++mi)
#pragma unroll
      for (int ni = 0; ni < 4; ++ni)
        acc[mi][ni] = __builtin_amdgcn_mfma_f32_16x16x32_bf16(af[mi], bfr[ni], acc[mi][ni], 0, 0, 0);
    __syncthreads();
  }

  const int col_l = lane & 15;
  const int rgrp = (lane >> 4) * 4;
#pragma unroll
  for (int ni = 0; ni < 4; ++ni) {
    const int col = bn * 128 + wn * 64 + ni * 16 + col_l;
    const float bias = bo[col];
#pragma unroll
    for (int mi = 0; mi < 4; ++mi) {
      const long row = (long)bm * 128 + wm * 64 + mi * 16 + rgrp;
#pragma unroll
      for (int r2 = 0; r2 < 4; ++r2)
        out[(row + r2) * 512 + col] = acc[mi][ni][r2] + bias;
    }
  }
}

extern "C" void kernel_launch(void* const* d_in, const int* in_sizes, int n_in,
                              void* d_out, int out_size, void* d_ws, size_t ws_size,
                              hipStream_t stream) {
  (void)in_sizes; (void)n_in; (void)out_size; (void)ws_size;
  const float* x  = (const float*)d_in[0];
  const float* Wq = (const float*)d_in[1];
  const float* bq = (const float*)d_in[2];
  const float* Wk = (const float*)d_in[3];
  const float* bk = (const float*)d_in[4];
  const float* Wv = (const float*)d_in[5];
  const float* bv = (const float*)d_in[6];
  const float* Wo = (const float*)d_in[7];
  const float* bo = (const float*)d_in[8];
  float* out = (float*)d_out;

  unsigned short* xb   = (unsigned short*)d_ws;            // 65536*512  bf16 = 64 MiB
  unsigned short* wt   = xb + (size_t)33554432;            // 1536*512   bf16 = 1.5 MiB
  unsigned short* kv   = wt + (size_t)786432;              // 65536*1024 bf16 = 128 MiB
  unsigned short* ctxb = kv + (size_t)67108864;            // 256*512    bf16 = 0.25 MiB

  cvt_x_kernel<<<16384, 256, 0, stream>>>(x, xb);
  prep_w_kernel<<<3072, 256, 0, stream>>>(Wk, Wv, Wo, wt);
  kv_gemm_kernel<<<dim3(8, 512), 256, 0, stream>>>(xb, wt, bk, bv, kv);
  attn_core_kernel<<<dim3(256, 8), 256, 0, stream>>>(x, Wq, bq, kv, ctxb);
  oproj_gemm_kernel<<<dim3(4, 2), 256, 0, stream>>>(ctxb, wt + (size_t)1024 * 512, bo, out);
}